// Round 3
// baseline (18.878 us; speedup 1.0000x reference)
//
#include <hip/hip_runtime.h>
#include <math.h>

// NormalizingFlow: 32 chained Affine(2) layers over 4,194,304 2-D points.
// The chain x <- W_i x + b_i composes into ONE affine map
//   x_out = M x + c,  M = W_31...W_0,  c = W_31(...(W_0*0+b_0)...)+b_31
// log_det = sum_i log|det W_i|.
//
// Single fused kernel, replay-optimized:
//  - each thread owns EXACTLY 4 float4s (2048 blk x 256 thr x 4 = 2,097,152),
//    all 4 loads issued before the compose barrier (64 B in flight/lane)
//  - thread 0 composes M,c in f64 into LDS; wave 1 of block 0 does log_det
//    in parallel (one log per lane + shuffle reduce)
//  - PLAIN cached stores (no nontemporal): the 67 MB working set fits the
//    256 MB Infinity Cache, so timed graph replays run at LLC bandwidth
//    instead of being forced to HBM.

#define NF_POINTS 4194304
#define NF_FLOWS  32
#define NF_GRID   2048
#define NF_BLOCK  256
#define NF_STRIDE (NF_GRID * NF_BLOCK)          // 524288 float4s per sweep

__global__ void __launch_bounds__(NF_BLOCK)
nf_fused_kernel(const float4* __restrict__ in,
                float4* __restrict__ out,
                const float* __restrict__ W,    // [32,2,2]
                const float* __restrict__ B,    // [32,2]
                float* __restrict__ logdet_out)
{
    __shared__ float sp[6];

    const int tid = threadIdx.x;
    const int i0  = blockIdx.x * NF_BLOCK + tid;

    // Issue all 4 loads before the barrier: HBM/L3 latency covers the
    // compose chain, and 64 B/lane outstanding maximizes MLP.
    float4 v0 = in[i0];
    float4 v1 = in[i0 + NF_STRIDE];
    float4 v2 = in[i0 + 2 * NF_STRIDE];
    float4 v3 = in[i0 + 3 * NF_STRIDE];

    if (tid == 0) {
        // Compose the affine chain in f64 (more accurate than the
        // reference's sequential f32 scan).
        double p00 = 1.0, p01 = 0.0, p10 = 0.0, p11 = 1.0;
        double c0 = 0.0, c1 = 0.0;
        for (int f = 0; f < NF_FLOWS; ++f) {
            const double w00 = (double)W[f * 4 + 0];
            const double w01 = (double)W[f * 4 + 1];
            const double w10 = (double)W[f * 4 + 2];
            const double w11 = (double)W[f * 4 + 3];
            const double b0  = (double)B[f * 2 + 0];
            const double b1  = (double)B[f * 2 + 1];
            const double n00 = w00 * p00 + w01 * p10;
            const double n01 = w00 * p01 + w01 * p11;
            const double n10 = w10 * p00 + w11 * p10;
            const double n11 = w10 * p01 + w11 * p11;
            const double nc0 = w00 * c0 + w01 * c1 + b0;
            const double nc1 = w10 * c0 + w11 * c1 + b1;
            p00 = n00; p01 = n01; p10 = n10; p11 = n11;
            c0 = nc0; c1 = nc1;
        }
        sp[0] = (float)p00; sp[1] = (float)p01;
        sp[2] = (float)p10; sp[3] = (float)p11;
        sp[4] = (float)c0;  sp[5] = (float)c1;
    } else if (blockIdx.x == 0 && tid >= 64 && tid < 96) {
        // Wave 1, lanes 0..31: one log|det W_f| per lane, shuffle-reduce.
        // Runs concurrently with thread 0's compose (different wave).
        const int f = tid - 64;
        const double w00 = (double)W[f * 4 + 0];
        const double w01 = (double)W[f * 4 + 1];
        const double w10 = (double)W[f * 4 + 2];
        const double w11 = (double)W[f * 4 + 3];
        double ld = log(fabs(w00 * w11 - w01 * w10));
        for (int off = 16; off; off >>= 1)
            ld += __shfl_down(ld, off, 32);
        if (f == 0) *logdet_out = (float)ld;
    }
    __syncthreads();

    const float m00 = sp[0], m01 = sp[1];
    const float m10 = sp[2], m11 = sp[3];
    const float cc0 = sp[4], cc1 = sp[5];

    float4 o;
    o.x = fmaf(m00, v0.x, fmaf(m01, v0.y, cc0));
    o.y = fmaf(m10, v0.x, fmaf(m11, v0.y, cc1));
    o.z = fmaf(m00, v0.z, fmaf(m01, v0.w, cc0));
    o.w = fmaf(m10, v0.z, fmaf(m11, v0.w, cc1));
    out[i0] = o;

    o.x = fmaf(m00, v1.x, fmaf(m01, v1.y, cc0));
    o.y = fmaf(m10, v1.x, fmaf(m11, v1.y, cc1));
    o.z = fmaf(m00, v1.z, fmaf(m01, v1.w, cc0));
    o.w = fmaf(m10, v1.z, fmaf(m11, v1.w, cc1));
    out[i0 + NF_STRIDE] = o;

    o.x = fmaf(m00, v2.x, fmaf(m01, v2.y, cc0));
    o.y = fmaf(m10, v2.x, fmaf(m11, v2.y, cc1));
    o.z = fmaf(m00, v2.z, fmaf(m01, v2.w, cc0));
    o.w = fmaf(m10, v2.z, fmaf(m11, v2.w, cc1));
    out[i0 + 2 * NF_STRIDE] = o;

    o.x = fmaf(m00, v3.x, fmaf(m01, v3.y, cc0));
    o.y = fmaf(m10, v3.x, fmaf(m11, v3.y, cc1));
    o.z = fmaf(m00, v3.z, fmaf(m01, v3.w, cc0));
    o.w = fmaf(m10, v3.z, fmaf(m11, v3.w, cc1));
    out[i0 + 3 * NF_STRIDE] = o;
}

extern "C" void kernel_launch(void* const* d_in, const int* in_sizes, int n_in,
                              void* d_out, int out_size, void* d_ws, size_t ws_size,
                              hipStream_t stream)
{
    const float* x = (const float*)d_in[0];   // [4194304, 2] f32
    const float* W = (const float*)d_in[1];   // [32, 2, 2]   f32
    const float* B = (const float*)d_in[2];   // [32, 2]      f32

    float* out = (float*)d_out;               // 8388608 x_out + 1 log_det

    // 2048 x 256 x 4 float4s == 2,097,152 == NF_POINTS/2 exactly.
    nf_fused_kernel<<<NF_GRID, NF_BLOCK, 0, stream>>>(
        (const float4*)x, (float4*)out, W, B,
        out + (size_t)NF_POINTS * 2);
}

// Round 5
// 15.429 us; speedup vs baseline: 1.2235x; 1.2235x over previous
//
#include <hip/hip_runtime.h>
#include <math.h>

// NormalizingFlow: 32 chained Affine(2) layers over 4,194,304 2-D points.
// The chain x <- W_i x + b_i composes into ONE affine map
//   x_out = M x + c,  M = W_31...W_0,  c = W_31(...(W_0*0+b_0)...)+b_31
// log_det = sum_i log|det W_i|.
//
// Single fused kernel, pure-streaming form:
//  - each thread owns EXACTLY 4 float4s (2048 blk x 256 thr x 4 = 2,097,152),
//    all 4 nontemporal 16B loads issued before the compose barrier
//  - thread 0 composes M,c in f64 into LDS; wave 1 of block 0 does log_det
//    in parallel (one log per lane + shuffle reduce)
//  - nontemporal 16B loads AND stores (dwordx4 nt): the harness's 268 MB
//    poison fills cycle the whole 256 MB LLC between replays, so cache
//    residency never helps (R3 lesson) — skip allocation entirely.
//  - NOTE: __builtin_nontemporal_* requires a NATIVE clang vector type,
//    not HIP_vector_type (R4 compile fix) -> ext_vector_type(4) float.

#define NF_POINTS 4194304
#define NF_FLOWS  32
#define NF_GRID   2048
#define NF_BLOCK  256
#define NF_STRIDE (NF_GRID * NF_BLOCK)          // 524288 vec4s per sweep

typedef float vfloat4 __attribute__((ext_vector_type(4)));

__global__ void __launch_bounds__(NF_BLOCK)
nf_fused_kernel(const vfloat4* __restrict__ in,
                vfloat4* __restrict__ out,
                const float* __restrict__ W,    // [32,2,2]
                const float* __restrict__ B,    // [32,2]
                float* __restrict__ logdet_out)
{
    __shared__ float sp[6];

    const int tid = threadIdx.x;
    const int i0  = blockIdx.x * NF_BLOCK + tid;

    // Issue all 4 loads before the barrier: memory latency covers the
    // compose chain, 64 B/lane outstanding maximizes MLP.
    vfloat4 v0 = __builtin_nontemporal_load(&in[i0]);
    vfloat4 v1 = __builtin_nontemporal_load(&in[i0 + NF_STRIDE]);
    vfloat4 v2 = __builtin_nontemporal_load(&in[i0 + 2 * NF_STRIDE]);
    vfloat4 v3 = __builtin_nontemporal_load(&in[i0 + 3 * NF_STRIDE]);

    if (tid == 0) {
        // Compose the affine chain in f64 (more accurate than the
        // reference's sequential f32 scan).
        double p00 = 1.0, p01 = 0.0, p10 = 0.0, p11 = 1.0;
        double c0 = 0.0, c1 = 0.0;
        for (int f = 0; f < NF_FLOWS; ++f) {
            const double w00 = (double)W[f * 4 + 0];
            const double w01 = (double)W[f * 4 + 1];
            const double w10 = (double)W[f * 4 + 2];
            const double w11 = (double)W[f * 4 + 3];
            const double b0  = (double)B[f * 2 + 0];
            const double b1  = (double)B[f * 2 + 1];
            const double n00 = w00 * p00 + w01 * p10;
            const double n01 = w00 * p01 + w01 * p11;
            const double n10 = w10 * p00 + w11 * p10;
            const double n11 = w10 * p01 + w11 * p11;
            const double nc0 = w00 * c0 + w01 * c1 + b0;
            const double nc1 = w10 * c0 + w11 * c1 + b1;
            p00 = n00; p01 = n01; p10 = n10; p11 = n11;
            c0 = nc0; c1 = nc1;
        }
        sp[0] = (float)p00; sp[1] = (float)p01;
        sp[2] = (float)p10; sp[3] = (float)p11;
        sp[4] = (float)c0;  sp[5] = (float)c1;
    } else if (blockIdx.x == 0 && tid >= 64 && tid < 96) {
        // Wave 1, lanes 0..31: one log|det W_f| per lane, shuffle-reduce.
        // Runs concurrently with thread 0's compose (different wave).
        const int f = tid - 64;
        const double w00 = (double)W[f * 4 + 0];
        const double w01 = (double)W[f * 4 + 1];
        const double w10 = (double)W[f * 4 + 2];
        const double w11 = (double)W[f * 4 + 3];
        double ld = log(fabs(w00 * w11 - w01 * w10));
        for (int off = 16; off; off >>= 1)
            ld += __shfl_down(ld, off, 32);
        if (f == 0) *logdet_out = (float)ld;
    }
    __syncthreads();

    const float m00 = sp[0], m01 = sp[1];
    const float m10 = sp[2], m11 = sp[3];
    const float cc0 = sp[4], cc1 = sp[5];

    vfloat4 o;
    o.x = fmaf(m00, v0.x, fmaf(m01, v0.y, cc0));
    o.y = fmaf(m10, v0.x, fmaf(m11, v0.y, cc1));
    o.z = fmaf(m00, v0.z, fmaf(m01, v0.w, cc0));
    o.w = fmaf(m10, v0.z, fmaf(m11, v0.w, cc1));
    __builtin_nontemporal_store(o, &out[i0]);

    o.x = fmaf(m00, v1.x, fmaf(m01, v1.y, cc0));
    o.y = fmaf(m10, v1.x, fmaf(m11, v1.y, cc1));
    o.z = fmaf(m00, v1.z, fmaf(m01, v1.w, cc0));
    o.w = fmaf(m10, v1.z, fmaf(m11, v1.w, cc1));
    __builtin_nontemporal_store(o, &out[i0 + NF_STRIDE]);

    o.x = fmaf(m00, v2.x, fmaf(m01, v2.y, cc0));
    o.y = fmaf(m10, v2.x, fmaf(m11, v2.y, cc1));
    o.z = fmaf(m00, v2.z, fmaf(m01, v2.w, cc0));
    o.w = fmaf(m10, v2.z, fmaf(m11, v2.w, cc1));
    __builtin_nontemporal_store(o, &out[i0 + 2 * NF_STRIDE]);

    o.x = fmaf(m00, v3.x, fmaf(m01, v3.y, cc0));
    o.y = fmaf(m10, v3.x, fmaf(m11, v3.y, cc1));
    o.z = fmaf(m00, v3.z, fmaf(m01, v3.w, cc0));
    o.w = fmaf(m10, v3.z, fmaf(m11, v3.w, cc1));
    __builtin_nontemporal_store(o, &out[i0 + 3 * NF_STRIDE]);
}

extern "C" void kernel_launch(void* const* d_in, const int* in_sizes, int n_in,
                              void* d_out, int out_size, void* d_ws, size_t ws_size,
                              hipStream_t stream)
{
    const float* x = (const float*)d_in[0];   // [4194304, 2] f32
    const float* W = (const float*)d_in[1];   // [32, 2, 2]   f32
    const float* B = (const float*)d_in[2];   // [32, 2]      f32

    float* out = (float*)d_out;               // 8388608 x_out + 1 log_det

    // 2048 x 256 x 4 vec4s == 2,097,152 == NF_POINTS/2 exactly.
    nf_fused_kernel<<<NF_GRID, NF_BLOCK, 0, stream>>>(
        (const vfloat4*)x, (vfloat4*)out, W, B,
        out + (size_t)NF_POINTS * 2);
}